// Round 5
// baseline (56.252 us; speedup 1.0000x reference)
//
#include <hip/hip_runtime.h>
#include <math.h>

#define BB 4
#define TT 4096
#define CC 1024
#define HH 64
#define MM (BB*TT)

typedef __attribute__((ext_vector_type(8))) short  short8;
typedef __attribute__((ext_vector_type(4))) short  short4v;
typedef __attribute__((ext_vector_type(4))) float  f32x4;

typedef const __attribute__((address_space(1))) unsigned int GU;
typedef __attribute__((address_space(3))) unsigned int LU;

static __device__ __forceinline__ unsigned short f2bf(float f) {
    union { float f; unsigned u; } v; v.f = f;
    unsigned r = v.u + 0x7FFF + ((v.u >> 16) & 1);
    return (unsigned short)(r >> 16);
}

// ---------------- Kernel 0: W -> W^T bf16 (tiny) ----------------
__global__ __launch_bounds__(256) void convw_kernel(
        const float* __restrict__ Wq, const float* __restrict__ Wk,
        const float* __restrict__ Wv, unsigned short* __restrict__ wtb) {
    __shared__ unsigned short sW[64][66];
    const int m    = blockIdx.x >> 4;
    const int cblk = blockIdx.x & 15;
    const float* W = (m == 0) ? Wq : (m == 1) ? Wk : Wv;
    const int lane = threadIdx.x & 63;
    const int w    = threadIdx.x >> 6;
    #pragma unroll
    for (int rep = 0; rep < 16; ++rep) {
        const int cl = w * 16 + rep;
        sW[cl][lane] = f2bf(W[(size_t)(cblk * 64 + cl) * HH + lane]);
    }
    __syncthreads();
    #pragma unroll
    for (int rep = 0; rep < 16; ++rep) {
        const int h2 = w * 16 + rep;
        wtb[(size_t)(m * 64 + h2) * CC + cblk * 64 + lane] = sW[lane][h2];
    }
}

// ---------------- Kernel 1: pipelined cvt + bf16 MFMA projection ----------------
// BM=32, BN=192, BK=64. grid=512, 512 threads = 8 waves (2 rg x 4 cg).
// A: direct global->reg (fp32->bf16 cvt), prefetched 1 K-step ahead.
// B: double-buffered LDS via global_load_lds, counted vmcnt(7) -- loads
// stay in flight across raw s_barrier (no __syncthreads drain).
__global__ __launch_bounds__(512, 4) void gemm_kernel(
        const float* __restrict__ x,
        const unsigned short* __restrict__ wtb,
        unsigned short* __restrict__ qb,
        unsigned short* __restrict__ kb,
        unsigned short* __restrict__ vt) {
    __shared__ unsigned short Bs[2][192 * 64];   // 2 x 24 KB, XOR-swizzled

    const int tid  = threadIdx.x;
    const int lane = tid & 63;
    const int w    = tid >> 6;
    const int l15  = lane & 15;
    const int lg   = lane >> 4;
    const int row0 = blockIdx.x * 32;
    const int rg   = (w >> 2) * 16;      // row group: 0 or 16
    const int wc   = (w & 3) * 48;       // col group base

    f32x4 acc[3];
    #pragma unroll
    for (int j = 0; j < 3; ++j) acc[j] = (f32x4){0.f, 0.f, 0.f, 0.f};

    // per-lane A source: row = row0 + rg + l15, k-octet base lg*8
    const float* xrow = x + (size_t)(row0 + rg + l15) * CC + lg * 8;

    // ---- prologue: stage B(0) -> buf0, load A(0) ----
    #pragma unroll
    for (int it = 0; it < 3; ++it) {
        const int lidx = it * 8192 + tid * 16;
        const int r  = lidx >> 7;
        const int cb = (((lidx & 127) >> 4) ^ (r & 7));
        const unsigned short* g = wtb + (size_t)r * CC + cb * 8;
        __builtin_amdgcn_global_load_lds((GU*)g,
            (LU*)((char*)Bs[0] + it * 8192 + w * 1024), 16, 0, 0);
    }
    float4 ac0 = *reinterpret_cast<const float4*>(xrow);
    float4 ac1 = *reinterpret_cast<const float4*>(xrow + 4);
    float4 ac2 = *reinterpret_cast<const float4*>(xrow + 32);
    float4 ac3 = *reinterpret_cast<const float4*>(xrow + 36);
    float4 an0, an1, an2, an3;

    const int swz = (l15 & 7) << 4;

    #pragma unroll
    for (int t = 0; t < 16; ++t) {
        if (t < 15) {
            const int kcn = (t + 1) * 64;
            char* bs = (char*)Bs[(t + 1) & 1];
            #pragma unroll
            for (int it = 0; it < 3; ++it) {
                const int lidx = it * 8192 + tid * 16;
                const int r  = lidx >> 7;
                const int cb = (((lidx & 127) >> 4) ^ (r & 7));
                const unsigned short* g = wtb + (size_t)r * CC + kcn + cb * 8;
                __builtin_amdgcn_global_load_lds((GU*)g,
                    (LU*)(bs + it * 8192 + w * 1024), 16, 0, 0);
            }
            an0 = *reinterpret_cast<const float4*>(xrow + kcn);
            an1 = *reinterpret_cast<const float4*>(xrow + kcn + 4);
            an2 = *reinterpret_cast<const float4*>(xrow + kcn + 32);
            an3 = *reinterpret_cast<const float4*>(xrow + kcn + 36);
            asm volatile("s_waitcnt vmcnt(7)" ::: "memory");  // B(t),A(t) landed
        } else {
            asm volatile("s_waitcnt vmcnt(0)" ::: "memory");
        }
        __builtin_amdgcn_s_barrier();     // B(t) visible to all waves

        // cvt A(t) -> fragments
        short8 af0, af1;
        af0[0] = (short)f2bf(ac0.x); af0[1] = (short)f2bf(ac0.y);
        af0[2] = (short)f2bf(ac0.z); af0[3] = (short)f2bf(ac0.w);
        af0[4] = (short)f2bf(ac1.x); af0[5] = (short)f2bf(ac1.y);
        af0[6] = (short)f2bf(ac1.z); af0[7] = (short)f2bf(ac1.w);
        af1[0] = (short)f2bf(ac2.x); af1[1] = (short)f2bf(ac2.y);
        af1[2] = (short)f2bf(ac2.z); af1[3] = (short)f2bf(ac2.w);
        af1[4] = (short)f2bf(ac3.x); af1[5] = (short)f2bf(ac3.y);
        af1[6] = (short)f2bf(ac3.z); af1[7] = (short)f2bf(ac3.w);

        const char* Bsc = (const char*)Bs[t & 1];
        short8 bf[3][2];
        #pragma unroll
        for (int nf = 0; nf < 3; ++nf)
            #pragma unroll
            for (int kh = 0; kh < 2; ++kh) {
                const int n = wc + nf * 16 + l15;
                bf[nf][kh] = *(const short8*)(Bsc + n * 128 + ((kh * 64 + lg * 16) ^ swz));
            }
        #pragma unroll
        for (int kh = 0; kh < 2; ++kh) {
            short8 af = kh ? af1 : af0;
            #pragma unroll
            for (int nf = 0; nf < 3; ++nf)
                acc[nf] = __builtin_amdgcn_mfma_f32_16x16x32_bf16(
                    af, bf[nf][kh], acc[nf], 0, 0, 0);
        }

        asm volatile("s_waitcnt lgkmcnt(0)" ::: "memory");
        __builtin_amdgcn_sched_barrier(0);
        __builtin_amdgcn_s_barrier();     // all waves done reading buf[t&1]

        ac0 = an0; ac1 = an1; ac2 = an2; ac3 = an3;
    }

    // ---- epilogue: q,k row-major bf16; v transposed vt[b][h][t] ----
    const int b = row0 >> 12;
    #pragma unroll
    for (int nf = 0; nf < 3; ++nf) {
        const int ng = wc + nf * 16 + l15;
        const int m  = ng >> 6, h = ng & 63;
        const int rowbase = row0 + rg + lg * 4;
        if (m == 2) {
            short4v pk;
            pk[0] = (short)f2bf(acc[nf][0]);
            pk[1] = (short)f2bf(acc[nf][1]);
            pk[2] = (short)f2bf(acc[nf][2]);
            pk[3] = (short)f2bf(acc[nf][3]);
            *reinterpret_cast<short4v*>(
                &vt[((size_t)(b * 64 + h)) * TT + (rowbase & (TT - 1))]) = pk;
        } else {
            unsigned short* dst = (m == 0) ? qb : kb;
            #pragma unroll
            for (int r = 0; r < 4; ++r)
                dst[(size_t)(rowbase + r) * HH + h] = f2bf(acc[nf][r]);
        }
    }
}

// ---------------- Kernel 2: MFMA windowed causal attention ----------------
// (unchanged from round 4)
__global__ __launch_bounds__(256) void attn_kernel(
        const unsigned short* __restrict__ qb,
        const unsigned short* __restrict__ kb,
        const unsigned short* __restrict__ vt,
        const float* __restrict__ decay,
        float* __restrict__ out) {
    __shared__ unsigned short P[4][16 * 168];

    const int lane = threadIdx.x & 63;
    const int w    = threadIdx.x >> 6;
    const int l15  = lane & 15;
    const int lg   = lane >> 4;
    const int qt   = blockIdx.x * 4 + w;
    const int gb   = qt >> 8;
    const int i0   = (qt & 255) << 4;

    const float dec = fabsf(decay[0]);
    const size_t bbase = (size_t)gb * TT;

    short8 af0, af1;
    {
        const unsigned short* qp = qb + (bbase + i0 + l15) * HH + lg * 8;
        af0 = *(const short8*)(qp);
        af1 = *(const short8*)(qp + 32);
    }

    float psum[4] = {0.f, 0.f, 0.f, 0.f};
    unsigned short* Pw = &P[w][0];

    if (i0 >= 144) {
        const int js = i0 - 144;
        const unsigned short* kp = kb + (bbase + js + l15) * HH + lg * 8;
        #pragma unroll
        for (int ts = 0; ts < 10; ++ts) {
            short8 b0 = *(const short8*)(kp + (size_t)ts * 16 * HH);
            short8 b1 = *(const short8*)(kp + (size_t)ts * 16 * HH + 32);
            f32x4 s = (f32x4){0.f, 0.f, 0.f, 0.f};
            s = __builtin_amdgcn_mfma_f32_16x16x32_bf16(af0, b0, s, 0, 0, 0);
            s = __builtin_amdgcn_mfma_f32_16x16x32_bf16(af1, b1, s, 0, 0, 0);
            const int d0 = 144 + lg * 4 - ts * 16 - l15;
            #pragma unroll
            for (int r = 0; r < 4; ++r) {
                const int d = d0 + r;
                float sv = s[r] * 0.125f - dec * (float)d - 12.0f;
                float p  = (ts == 9 && d < 0) ? 0.0f : __expf(sv);
                psum[r] += p;
                Pw[(lg * 4 + r) * 168 + ts * 16 + l15] = f2bf(p);
            }
        }
        #pragma unroll
        for (int off = 1; off < 16; off <<= 1)
            #pragma unroll
            for (int r = 0; r < 4; ++r)
                psum[r] += __shfl_xor(psum[r], off, 64);

        asm volatile("s_waitcnt lgkmcnt(0)" ::: "memory");
        __builtin_amdgcn_sched_barrier(0);

        f32x4 oacc[4];
        #pragma unroll
        for (int ht = 0; ht < 4; ++ht) oacc[ht] = (f32x4){0.f, 0.f, 0.f, 0.f};
        const unsigned short* vp = vt + ((size_t)(gb * 64) + l15) * TT + js + lg * 8;

        __builtin_amdgcn_s_setprio(1);
        #pragma unroll
        for (int kt = 0; kt < 5; ++kt) {
            short8 pa = *(const short8*)((const char*)Pw + l15 * 336 + kt * 64 + lg * 16);
            #pragma unroll
            for (int ht = 0; ht < 4; ++ht) {
                short8 bv = *(const short8*)(vp + (size_t)ht * 16 * TT + kt * 32);
                oacc[ht] = __builtin_amdgcn_mfma_f32_16x16x32_bf16(pa, bv, oacc[ht], 0, 0, 0);
            }
        }
        __builtin_amdgcn_s_setprio(0);

        float inv[4];
        #pragma unroll
        for (int r = 0; r < 4; ++r) inv[r] = 1.0f / psum[r];
        float* op = out + (bbase + i0 + lg * 4) * HH + l15;
        #pragma unroll
        for (int ht = 0; ht < 4; ++ht)
            #pragma unroll
            for (int r = 0; r < 4; ++r)
                op[(size_t)r * HH + ht * 16] = oacc[ht][r] * inv[r];
    } else {
        const int NS = (i0 >> 4) + 1;
        const int NK = (NS + 1) >> 1;
        const int dbase = i0 + lg * 4 - l15;
        const unsigned short* kp = kb + (bbase + l15) * HH + lg * 8;

        for (int ts = 0; ts < NS; ++ts) {
            short8 b0 = *(const short8*)(kp);
            short8 b1 = *(const short8*)(kp + 32);
            kp += 16 * HH;
            f32x4 s = (f32x4){0.f, 0.f, 0.f, 0.f};
            s = __builtin_amdgcn_mfma_f32_16x16x32_bf16(af0, b0, s, 0, 0, 0);
            s = __builtin_amdgcn_mfma_f32_16x16x32_bf16(af1, b1, s, 0, 0, 0);
            const int d0 = dbase - ts * 16;
            #pragma unroll
            for (int r = 0; r < 4; ++r) {
                const int d = d0 + r;
                float sv = s[r] * 0.125f - dec * (float)d - 12.0f;
                float p  = (d < 0) ? 0.0f : __expf(sv);
                psum[r] += p;
                Pw[(lg * 4 + r) * 168 + ts * 16 + l15] = f2bf(p);
            }
        }
        if (NS & 1) {
            #pragma unroll
            for (int r = 0; r < 4; ++r)
                Pw[(lg * 4 + r) * 168 + NS * 16 + l15] = 0;
        }
        #pragma unroll
        for (int off = 1; off < 16; off <<= 1)
            #pragma unroll
            for (int r = 0; r < 4; ++r)
                psum[r] += __shfl_xor(psum[r], off, 64);

        asm volatile("s_waitcnt lgkmcnt(0)" ::: "memory");
        __builtin_amdgcn_sched_barrier(0);

        f32x4 oacc[4];
        #pragma unroll
        for (int ht = 0; ht < 4; ++ht) oacc[ht] = (f32x4){0.f, 0.f, 0.f, 0.f};
        const unsigned short* vp = vt + ((size_t)(gb * 64) + l15) * TT + lg * 8;

        for (int kt = 0; kt < NK; ++kt) {
            short8 pa = *(const short8*)((const char*)Pw + l15 * 336 + kt * 64 + lg * 16);
            #pragma unroll
            for (int ht = 0; ht < 4; ++ht) {
                short8 bv = *(const short8*)(vp + (size_t)ht * 16 * TT + kt * 32);
                oacc[ht] = __builtin_amdgcn_mfma_f32_16x16x32_bf16(pa, bv, oacc[ht], 0, 0, 0);
            }
        }

        float inv[4];
        #pragma unroll
        for (int r = 0; r < 4; ++r) inv[r] = 1.0f / psum[r];
        float* op = out + (bbase + i0 + lg * 4) * HH + l15;
        #pragma unroll
        for (int ht = 0; ht < 4; ++ht)
            #pragma unroll
            for (int r = 0; r < 4; ++r)
                op[(size_t)r * HH + ht * 16] = oacc[ht][r] * inv[r];
    }
}

extern "C" void kernel_launch(void* const* d_in, const int* in_sizes, int n_in,
                              void* d_out, int out_size, void* d_ws, size_t ws_size,
                              hipStream_t stream) {
    const float* x     = (const float*)d_in[0];
    const float* Wq    = (const float*)d_in[1];
    const float* Wk    = (const float*)d_in[2];
    const float* Wv    = (const float*)d_in[3];
    const float* decay = (const float*)d_in[4];
    float* out = (float*)d_out;

    unsigned short* qb  = (unsigned short*)d_ws;          // 2 MB
    unsigned short* kb  = qb + (size_t)MM * HH;           // 2 MB
    unsigned short* vt  = kb + (size_t)MM * HH;           // 2 MB (transposed)
    unsigned short* wtb = vt + (size_t)MM * HH;           // 384 KB

    convw_kernel<<<48, 256, 0, stream>>>(Wq, Wk, Wv, wtb);
    gemm_kernel<<<MM / 32, 512, 0, stream>>>(x, wtb, qb, kb, vt);
    attn_kernel<<<MM / 64, 256, 0, stream>>>(qb, kb, vt, decay, out);
}